// Round 10
// baseline (408.362 us; speedup 1.0000x reference)
//
#include <hip/hip_runtime.h>

// Problem constants (fixed by setup_inputs: H=W=4096, offset=16)
constexpr int W = 4096;
constexpr int H = 4096;
constexpr int HW = W * H;

constexpr int BX = 64, BY = 4;      // 256 threads; wave = one 256-px row
constexpr int TILE_W = BX * 4;      // 256 px
constexpr int GRID_X = W / TILE_W;  // 16
constexpr int GRID_Y = H / BY;      // 1024

constexpr unsigned CAP2 = 1u << 20; // d==2 list capacity (4 MB)
constexpr unsigned CAP3 = 1u << 14; // d>=3 list capacity (64 KB)

typedef unsigned char u8;
typedef unsigned int u32;

__device__ __forceinline__ float clamp01(float v) { return fminf(fmaxf(v, 0.f), 1.f); }
__device__ __forceinline__ float4 ld4(const float* p) { return *reinterpret_cast<const float4*>(p); }
__device__ __forceinline__ void st4(float* p, float4 v) { *reinterpret_cast<float4*>(p) = v; }
__device__ __forceinline__ float4 z4() { return make_float4(0.f, 0.f, 0.f, 0.f); }
__device__ __forceinline__ float rcp_f(float x) { return __builtin_amdgcn_rcpf(x); }

// Rare-path distance classification, assumes 3x3 neighborhood has no mask:
// 5x5 ring check (-> 2), then expanding Chebyshev rings r=3..16.
__device__ __attribute__((noinline)) u32 far_distance(
    const float* __restrict__ alpha, int x, int y)
{
    for (int dy = -2; dy <= 2; ++dy) {
        int yy = y + dy;
        if (yy < 0 || yy >= H) continue;
        if (dy == -2 || dy == 2) {
            for (int dx = -2; dx <= 2; ++dx) {
                int xx = x + dx;
                if (xx < 0 || xx >= W) continue;
                if (alpha[yy * W + xx] > 0.f) return 2;
            }
        } else {
            if (x - 2 >= 0 && alpha[yy * W + x - 2] > 0.f) return 2;
            if (x + 2 < W && alpha[yy * W + x + 2] > 0.f) return 2;
        }
    }
    for (int r = 3; r <= 16; ++r) {
        bool f = false;
        for (int dx = -r; dx <= r && !f; ++dx) {
            int gx = x + dx;
            if (gx < 0 || gx >= W) continue;
            int gy = y - r;
            if (gy >= 0 && alpha[gy * W + gx] > 0.f) f = true;
            gy = y + r;
            if (!f && gy < H && alpha[gy * W + gx] > 0.f) f = true;
        }
        for (int dy = -r + 1; dy <= r - 1 && !f; ++dy) {
            int gy = y + dy;
            if (gy < 0 || gy >= H) continue;
            int gx = x - r;
            if (gx >= 0 && alpha[gy * W + gx] > 0.f) f = true;
            gx = x + r;
            if (!f && gx < W && alpha[gy * W + gx] > 0.f) f = true;
        }
        if (f) return r;
    }
    return 255;
}

// Exact distance of any pixel (tail3 only, ~tens of evals total).
__device__ u32 d_of(const float* __restrict__ alpha, int x, int y) {
    if (alpha[y * W + x] > 0.f) return 0;
    for (int dy = -1; dy <= 1; ++dy) {
        int yy = y + dy;
        if (yy < 0 || yy >= H) continue;
        for (int dx = -1; dx <= 1; ++dx) {
            int xx = x + dx;
            if (xx < 0 || xx >= W) continue;
            if (alpha[yy * W + xx] > 0.f) return 1;
        }
    }
    return far_distance(alpha, x, y);
}

__device__ __forceinline__ float4 vsum4(float4 u, float4 c, float4 d,
                                        float4 mU, float4 mC, float4 mD)
{
    float4 r;
    r.x = u.x * mU.x + c.x * mC.x + d.x * mD.x;
    r.y = u.y * mU.y + c.y * mC.y + d.y * mD.y;
    r.z = u.z * mU.z + c.z * mC.z + d.z * mD.z;
    r.w = u.w * mU.w + c.w * mC.w + d.w * mD.w;
    return r;
}

// Pass 1 (R3 champion structure): streaming separable 3x3 box-sums; no LDS,
// no barrier, one output row per wave, horizontal halo via shuffles.
__global__ __launch_bounds__(BX * BY) void pass1_kernel(
    const float* __restrict__ rgb, const float* __restrict__ alpha,
    float* __restrict__ out,
    u32* __restrict__ cnts, u32* __restrict__ list2, u32* __restrict__ list3)
{
    const int tx = threadIdx.x;               // 0..63 (one wave per row)
    const int ty = threadIdx.y;               // 0..3
    const int x0 = blockIdx.x * TILE_W + tx * 4;
    const int y  = blockIdx.y * BY + ty;
    const int p0 = y * W + x0;
    const bool up = (y > 0), dn = (y < H - 1);

    const float* Gp = rgb + HW;
    const float* Bp = rgb + 2 * HW;

    // ---- issue all 12 row loads up front ----
    float4 aU = up ? ld4(alpha + p0 - W) : z4();
    float4 aC = ld4(alpha + p0);
    float4 aD = dn ? ld4(alpha + p0 + W) : z4();
    float4 rU = up ? ld4(rgb + p0 - W) : z4();
    float4 rC = ld4(rgb + p0);
    float4 rD = dn ? ld4(rgb + p0 + W) : z4();
    float4 gU = up ? ld4(Gp + p0 - W) : z4();
    float4 gC = ld4(Gp + p0);
    float4 gD = dn ? ld4(Gp + p0 + W) : z4();
    float4 bU = up ? ld4(Bp + p0 - W) : z4();
    float4 bC = ld4(Bp + p0);
    float4 bD = dn ? ld4(Bp + p0 + W) : z4();

    float4 mU = make_float4(aU.x > 0.f, aU.y > 0.f, aU.z > 0.f, aU.w > 0.f);
    float4 mC = make_float4(aC.x > 0.f, aC.y > 0.f, aC.z > 0.f, aC.w > 0.f);
    float4 mD = make_float4(aD.x > 0.f, aD.y > 0.f, aD.z > 0.f, aD.w > 0.f);

    float4 vw;
    vw.x = mU.x + mC.x + mD.x;
    vw.y = mU.y + mC.y + mD.y;
    vw.z = mU.z + mC.z + mD.z;
    vw.w = mU.w + mC.w + mD.w;
    float4 vr = vsum4(rU, rC, rD, mU, mC, mD);
    float4 vg = vsum4(gU, gC, gD, mU, mC, mD);
    float4 vb = vsum4(bU, bC, bD, mU, mC, mD);

    // ---- horizontal halo: neighbor lane's edge vertical sums ----
    float lw = __shfl_up(vw.w, 1), rw = __shfl_down(vw.x, 1);
    float lr = __shfl_up(vr.w, 1), rr = __shfl_down(vr.x, 1);
    float lg = __shfl_up(vg.w, 1), rg = __shfl_down(vg.x, 1);
    float lb = __shfl_up(vb.w, 1), rb = __shfl_down(vb.x, 1);

    // tile-edge halo columns: lanes 0 / 63 compute from global (predicated)
    if (tx == 0 || tx == BX - 1) {
        int xh = (tx == 0) ? x0 - 1 : x0 + 4;
        float hr = 0.f, hg = 0.f, hb = 0.f, hw = 0.f;
        if (xh >= 0 && xh < W) {
            #pragma unroll
            for (int dy = -1; dy <= 1; ++dy) {
                int yy = y + dy;
                if (yy < 0 || yy >= H) continue;
                int q = yy * W + xh;
                float m = (alpha[q] > 0.f) ? 1.f : 0.f;
                hw += m;
                hr += m * rgb[q];
                hg += m * Gp[q];
                hb += m * Bp[q];
            }
        }
        if (tx == 0) { lw = hw; lr = hr; lg = hg; lb = hb; }
        else         { rw = hw; rr = hr; rg = hg; rb = hb; }
    }

    float swv[4] = { lw + vw.x + vw.y, vw.x + vw.y + vw.z,
                     vw.y + vw.z + vw.w, vw.z + vw.w + rw };
    float srv[4] = { lr + vr.x + vr.y, vr.x + vr.y + vr.z,
                     vr.y + vr.z + vr.w, vr.z + vr.w + rr };
    float sgv[4] = { lg + vg.x + vg.y, vg.x + vg.y + vg.z,
                     vg.y + vg.z + vg.w, vg.z + vg.w + rg };
    float sbv[4] = { lb + vb.x + vb.y, vb.x + vb.y + vb.z,
                     vb.y + vb.z + vb.w, vb.z + vb.w + rb };

    const float mca[4] = {mC.x, mC.y, mC.z, mC.w};
    const float rca[4] = {rC.x, rC.y, rC.z, rC.w};
    const float gca[4] = {gC.x, gC.y, gC.z, gC.w};
    const float bca[4] = {bC.x, bC.y, bC.z, bC.w};

    float o0[4], o1[4], o2[4];

    #pragma unroll
    for (int i = 0; i < 4; ++i) {
        if (mca[i] > 0.f) {
            o0[i] = rca[i]; o1[i] = gca[i]; o2[i] = bca[i];
        } else if (swv[i] > 0.f) {
            float inv = rcp_f(swv[i] + 1e-7f);
            o0[i] = srv[i] * inv; o1[i] = sgv[i] * inv; o2[i] = sbv[i] * inv;
        } else {
            o0[i] = 0.f; o1[i] = 0.f; o2[i] = 0.f;
            u32 d = far_distance(alpha, x0 + i, y);
            if (d == 2) {
                u32 k = atomicAdd(&cnts[0], 1u);
                if (k < CAP2) list2[k] = (u32)(p0 + i);
            } else if (d <= 16) {
                u32 k = atomicAdd(&cnts[1], 1u);
                if (k < CAP3) list3[k] = (u32)(p0 + i) | (d << 24);
            }
        }
    }

    st4(out + p0, make_float4(clamp01(o0[0]), clamp01(o0[1]),
                              clamp01(o0[2]), clamp01(o0[3])));
    st4(out + HW + p0, make_float4(clamp01(o1[0]), clamp01(o1[1]),
                                   clamp01(o1[2]), clamp01(o1[3])));
    st4(out + 2 * HW + p0, make_float4(clamp01(o2[0]), clamp01(o2[1]),
                                       clamp01(o2[2]), clamp01(o2[3])));
}

// t=2: list-driven.  Neighbor q has d(q)==1 iff alpha[q]<=0 and its 3x3
// alpha-neighborhood has any >0 — derived from a 5x5 alpha window (no dmap).
// (All 9 neighbors of a d==2 pixel have d>=1, so alpha[q]<=0 holds for all.)
__global__ __launch_bounds__(256) void tail2_kernel(
    const float* __restrict__ alpha, float* __restrict__ out,
    const u32* __restrict__ cnts, const u32* __restrict__ list2)
{
    u32 n = cnts[0];
    if (n > CAP2) n = CAP2;
    for (u32 idx = blockIdx.x * 256u + threadIdx.x; idx < n;
         idx += gridDim.x * 256u) {
        u32 p = list2[idx];
        int y = (int)(p >> 12), x = (int)(p & (W - 1));

        float mw[5][5];
        #pragma unroll
        for (int dy = -2; dy <= 2; ++dy) {
            int yy = y + dy;
            bool vy = (yy >= 0) && (yy < H);
            #pragma unroll
            for (int dx = -2; dx <= 2; ++dx) {
                int xx = x + dx;
                bool v = vy && (xx >= 0) && (xx < W);
                mw[dy + 2][dx + 2] = v ? ((alpha[yy * W + xx] > 0.f) ? 1.f : 0.f) : 0.f;
            }
        }

        float s0 = 0.f, s1 = 0.f, s2 = 0.f, cw = 0.f;
        #pragma unroll
        for (int dy = -1; dy <= 1; ++dy) {
            #pragma unroll
            for (int dx = -1; dx <= 1; ++dx) {
                int qx = x + dx, qy = y + dy;
                if (qx < 0 || qx >= W || qy < 0 || qy >= H) continue;
                float any =
                    mw[dy + 1][dx + 1] + mw[dy + 1][dx + 2] + mw[dy + 1][dx + 3] +
                    mw[dy + 2][dx + 1] + mw[dy + 2][dx + 2] + mw[dy + 2][dx + 3] +
                    mw[dy + 3][dx + 1] + mw[dy + 3][dx + 2] + mw[dy + 3][dx + 3];
                if (any > 0.f) {
                    int q = qy * W + qx;
                    cw += 1.f;
                    s0 += out[q]; s1 += out[HW + q]; s2 += out[2 * HW + q];
                }
            }
        }
        float inv = rcp_f(cw + 1e-7f);
        int pp = y * W + x;
        out[pp]          = clamp01(s0 * inv);
        out[HW + pp]     = clamp01(s1 * inv);
        out[2 * HW + pp] = clamp01(s2 * inv);
    }
}

// t=3..16: single block over the compacted d>=3 list (expected ~0-2 entries).
__global__ __launch_bounds__(256) void tail3_kernel(
    const float* __restrict__ alpha, float* __restrict__ out,
    const u32* __restrict__ cnts, const u32* __restrict__ list3)
{
    u32 n = cnts[1];
    if (n > CAP3) n = CAP3;
    if (n == 0) return;
    for (int t = 3; t <= 16; ++t) {
        for (u32 i = threadIdx.x; i < n; i += 256u) {
            u32 e = list3[i];
            if ((e >> 24) != (u32)t) continue;
            int p = (int)(e & 0xFFFFFFu);
            int y = p >> 12, x = p & (W - 1);
            float s0 = 0.f, s1 = 0.f, s2 = 0.f, cw = 0.f;
            for (int dy = -1; dy <= 1; ++dy) {
                int qy = y + dy;
                if (qy < 0 || qy >= H) continue;
                for (int dx = -1; dx <= 1; ++dx) {
                    int qx = x + dx;
                    if (qx < 0 || qx >= W) continue;
                    if (dx == 0 && dy == 0) continue;
                    if (d_of(alpha, qx, qy) == (u32)(t - 1)) {
                        int q = qy * W + qx;
                        cw += 1.f;
                        s0 += out[q]; s1 += out[HW + q]; s2 += out[2 * HW + q];
                    }
                }
            }
            float inv = rcp_f(cw + 1e-7f);
            out[p]          = clamp01(s0 * inv);
            out[HW + p]     = clamp01(s1 * inv);
            out[2 * HW + p] = clamp01(s2 * inv);
        }
        __syncthreads();
    }
}

extern "C" void kernel_launch(void* const* d_in, const int* in_sizes, int n_in,
                              void* d_out, int out_size, void* d_ws, size_t ws_size,
                              hipStream_t stream) {
    const float* rgb   = (const float*)d_in[0];
    const float* alpha = (const float*)d_in[1];
    float* out = (float*)d_out;

    // ws layout: [64B counters][list2 (4MB)][list3 (64KB)]
    u32* cnts  = (u32*)d_ws;
    u32* list2 = (u32*)((char*)d_ws + 64);
    u32* list3 = list2 + CAP2;

    (void)hipMemsetAsync(cnts, 0, 64, stream);

    pass1_kernel<<<dim3(GRID_X, GRID_Y), dim3(BX, BY), 0, stream>>>(
        rgb, alpha, out, cnts, list2, list3);
    tail2_kernel<<<256, 256, 0, stream>>>(alpha, out, cnts, list2);
    tail3_kernel<<<1, 256, 0, stream>>>(alpha, out, cnts, list3);
}

// Round 11
// 160.386 us; speedup vs baseline: 2.5461x; 2.5461x over previous
//
#include <hip/hip_runtime.h>

// Problem constants (fixed by setup_inputs: H=W=4096, offset=16)
constexpr int W = 4096;
constexpr int H = 4096;
constexpr int HW = W * H;

constexpr int BX = 64, BY = 4;      // 256 threads; wave = one 256-px row
constexpr int TILE_W = BX * 4;      // 256 px
constexpr int GRID_X = W / TILE_W;  // 16
constexpr int GRID_Y = H / BY;      // 1024

typedef unsigned char u8;
typedef unsigned int u32;

__device__ __forceinline__ float clamp01(float v) { return fminf(fmaxf(v, 0.f), 1.f); }
__device__ __forceinline__ float4 ld4(const float* p) { return *reinterpret_cast<const float4*>(p); }
__device__ __forceinline__ void st4(float* p, float4 v) { *reinterpret_cast<float4*>(p) = v; }
__device__ __forceinline__ float4 z4() { return make_float4(0.f, 0.f, 0.f, 0.f); }
__device__ __forceinline__ float rcp_f(float x) { return __builtin_amdgcn_rcpf(x); }

// Rare-path distance classification (~0.2% of pixels): 5x5 ring, then
// expanding Chebyshev rings r=3..16 (~1e-7 of pixels).
__device__ __attribute__((noinline)) u32 far_distance(
    const float* __restrict__ alpha, int x, int y)
{
    for (int dy = -2; dy <= 2; ++dy) {
        int yy = y + dy;
        if (yy < 0 || yy >= H) continue;
        if (dy == -2 || dy == 2) {
            for (int dx = -2; dx <= 2; ++dx) {
                int xx = x + dx;
                if (xx < 0 || xx >= W) continue;
                if (alpha[yy * W + xx] > 0.f) return 2;
            }
        } else {
            if (x - 2 >= 0 && alpha[yy * W + x - 2] > 0.f) return 2;
            if (x + 2 < W && alpha[yy * W + x + 2] > 0.f) return 2;
        }
    }
    for (int r = 3; r <= 16; ++r) {
        bool f = false;
        for (int dx = -r; dx <= r && !f; ++dx) {
            int gx = x + dx;
            if (gx < 0 || gx >= W) continue;
            int gy = y - r;
            if (gy >= 0 && alpha[gy * W + gx] > 0.f) f = true;
            gy = y + r;
            if (!f && gy < H && alpha[gy * W + gx] > 0.f) f = true;
        }
        for (int dy = -r + 1; dy <= r - 1 && !f; ++dy) {
            int gy = y + dy;
            if (gy < 0 || gy >= H) continue;
            int gx = x - r;
            if (gx >= 0 && alpha[gy * W + gx] > 0.f) f = true;
            gx = x + r;
            if (!f && gx < W && alpha[gy * W + gx] > 0.f) f = true;
        }
        if (f) return r;
    }
    return 255;
}

__device__ __forceinline__ float4 vsum4(float4 u, float4 c, float4 d,
                                        float4 mU, float4 mC, float4 mD)
{
    float4 r;
    r.x = u.x * mU.x + c.x * mC.x + d.x * mD.x;
    r.y = u.y * mU.y + c.y * mC.y + d.y * mD.y;
    r.z = u.z * mU.z + c.z * mC.z + d.z * mD.z;
    r.w = u.w * mU.w + c.w * mC.w + d.w * mD.w;
    return r;
}

// Pass 1 (champion, measured 127 us): streaming separable 3x3 box-sums;
// no LDS, no barrier, no hot atomics.  d-classification goes to a dmap
// (uchar4 store) — the d>=3 list atomic fires ~0-2 times per image.
__global__ __launch_bounds__(BX * BY) void pass1_kernel(
    const float* __restrict__ rgb, const float* __restrict__ alpha,
    float* __restrict__ out, u8* __restrict__ dmap,
    u32* __restrict__ cnt, int* __restrict__ list, u32 cap)
{
    const int tx = threadIdx.x;               // 0..63 (one wave per row)
    const int ty = threadIdx.y;               // 0..3
    const int x0 = blockIdx.x * TILE_W + tx * 4;
    const int y  = blockIdx.y * BY + ty;
    const int p0 = y * W + x0;
    const bool up = (y > 0), dn = (y < H - 1);

    const float* Gp = rgb + HW;
    const float* Bp = rgb + 2 * HW;

    // ---- issue all 12 row loads up front (max memory-level parallelism) ----
    float4 aU = up ? ld4(alpha + p0 - W) : z4();
    float4 aC = ld4(alpha + p0);
    float4 aD = dn ? ld4(alpha + p0 + W) : z4();
    float4 rU = up ? ld4(rgb + p0 - W) : z4();
    float4 rC = ld4(rgb + p0);
    float4 rD = dn ? ld4(rgb + p0 + W) : z4();
    float4 gU = up ? ld4(Gp + p0 - W) : z4();
    float4 gC = ld4(Gp + p0);
    float4 gD = dn ? ld4(Gp + p0 + W) : z4();
    float4 bU = up ? ld4(Bp + p0 - W) : z4();
    float4 bC = ld4(Bp + p0);
    float4 bD = dn ? ld4(Bp + p0 + W) : z4();

    float4 mU = make_float4(aU.x > 0.f, aU.y > 0.f, aU.z > 0.f, aU.w > 0.f);
    float4 mC = make_float4(aC.x > 0.f, aC.y > 0.f, aC.z > 0.f, aC.w > 0.f);
    float4 mD = make_float4(aD.x > 0.f, aD.y > 0.f, aD.z > 0.f, aD.w > 0.f);

    float4 vw;
    vw.x = mU.x + mC.x + mD.x;
    vw.y = mU.y + mC.y + mD.y;
    vw.z = mU.z + mC.z + mD.z;
    vw.w = mU.w + mC.w + mD.w;
    float4 vr = vsum4(rU, rC, rD, mU, mC, mD);
    float4 vg = vsum4(gU, gC, gD, mU, mC, mD);
    float4 vb = vsum4(bU, bC, bD, mU, mC, mD);

    // ---- horizontal halo: neighbor lane's edge vertical sums ----
    float lw = __shfl_up(vw.w, 1), rw = __shfl_down(vw.x, 1);
    float lr = __shfl_up(vr.w, 1), rr = __shfl_down(vr.x, 1);
    float lg = __shfl_up(vg.w, 1), rg = __shfl_down(vg.x, 1);
    float lb = __shfl_up(vb.w, 1), rb = __shfl_down(vb.x, 1);

    // tile-edge halo columns: lanes 0 / 63 compute from global (predicated)
    if (tx == 0 || tx == BX - 1) {
        int xh = (tx == 0) ? x0 - 1 : x0 + 4;
        float hr = 0.f, hg = 0.f, hb = 0.f, hw = 0.f;
        if (xh >= 0 && xh < W) {
            #pragma unroll
            for (int dy = -1; dy <= 1; ++dy) {
                int yy = y + dy;
                if (yy < 0 || yy >= H) continue;
                int q = yy * W + xh;
                float m = (alpha[q] > 0.f) ? 1.f : 0.f;
                hw += m;
                hr += m * rgb[q];
                hg += m * Gp[q];
                hb += m * Bp[q];
            }
        }
        if (tx == 0) { lw = hw; lr = hr; lg = hg; lb = hb; }
        else         { rw = hw; rr = hr; rg = hg; rb = hb; }
    }

    float sw[4] = { lw + vw.x + vw.y, vw.x + vw.y + vw.z,
                    vw.y + vw.z + vw.w, vw.z + vw.w + rw };
    float sr[4] = { lr + vr.x + vr.y, vr.x + vr.y + vr.z,
                    vr.y + vr.z + vr.w, vr.z + vr.w + rr };
    float sg[4] = { lg + vg.x + vg.y, vg.x + vg.y + vg.z,
                    vg.y + vg.z + vg.w, vg.z + vg.w + rg };
    float sb[4] = { lb + vb.x + vb.y, vb.x + vb.y + vb.z,
                    vb.y + vb.z + vb.w, vb.z + vb.w + rb };

    const float mca[4] = {mC.x, mC.y, mC.z, mC.w};
    const float rca[4] = {rC.x, rC.y, rC.z, rC.w};
    const float gca[4] = {gC.x, gC.y, gC.z, gC.w};
    const float bca[4] = {bC.x, bC.y, bC.z, bC.w};

    float o_r[4], o_g[4], o_b[4];
    u32 dv[4];

    #pragma unroll
    for (int i = 0; i < 4; ++i) {
        if (mca[i] > 0.f) {
            dv[i] = 0;
            o_r[i] = rca[i]; o_g[i] = gca[i]; o_b[i] = bca[i];
        } else if (sw[i] > 0.f) {
            dv[i] = 1;
            float inv = rcp_f(sw[i] + 1e-7f);
            o_r[i] = sr[i] * inv; o_g[i] = sg[i] * inv; o_b[i] = sb[i] * inv;
        } else {
            u32 d = far_distance(alpha, x0 + i, y);
            dv[i] = d;
            o_r[i] = 0.f; o_g[i] = 0.f; o_b[i] = 0.f;
            if (d >= 3 && d <= 16) {
                u32 idx = atomicAdd(cnt, 1u);
                if (idx < cap) list[idx] = p0 + i;
            }
        }
    }

    st4(out + p0, make_float4(clamp01(o_r[0]), clamp01(o_r[1]),
                              clamp01(o_r[2]), clamp01(o_r[3])));
    st4(out + HW + p0, make_float4(clamp01(o_g[0]), clamp01(o_g[1]),
                                   clamp01(o_g[2]), clamp01(o_g[3])));
    st4(out + 2 * HW + p0, make_float4(clamp01(o_b[0]), clamp01(o_b[1]),
                                       clamp01(o_b[2]), clamp01(o_b[3])));
    *reinterpret_cast<uchar4*>(dmap + p0) =
        make_uchar4((u8)dv[0], (u8)dv[1], (u8)dv[2], (u8)dv[3]);
}

// Fill one pixel at ring t (t >= 2): average of 3x3 neighbors with d == t-1.
// (For a d==t pixel, every neighbor has d >= t-1, so "filled" == "d == t-1".)
__device__ __forceinline__ void fill_pixel(float* __restrict__ out,
                                           const u8* __restrict__ dmap,
                                           int x, int y, int t)
{
    float s0 = 0.f, s1 = 0.f, s2 = 0.f;
    int cnt = 0;
    #pragma unroll
    for (int dy = -1; dy <= 1; ++dy) {
        int ny = y + dy;
        if (ny < 0 || ny >= H) continue;
        #pragma unroll
        for (int dx = -1; dx <= 1; ++dx) {
            int nx = x + dx;
            if (nx < 0 || nx >= W) continue;
            int q = ny * W + nx;
            if (dmap[q] == (u8)(t - 1)) {
                cnt++;
                s0 += out[q];
                s1 += out[HW + q];
                s2 += out[2 * HW + q];
            }
        }
    }
    float inv = rcp_f((float)cnt + 1e-7f);
    int p = y * W + x;
    out[p]          = clamp01(s0 * inv);
    out[HW + p]     = clamp01(s1 * inv);
    out[2 * HW + p] = clamp01(s2 * inv);
}

__device__ __forceinline__ u32 has_byte2(u32 x) {
    u32 v = x ^ 0x02020202u;
    return (v - 0x01010101u) & ~v & 0x80808080u;
}

// t=2 pass: one thread gates on 16 dmap bytes (uint4).
__global__ __launch_bounds__(256) void tail_dense(
    float* __restrict__ out, const u8* __restrict__ dmap)
{
    int idx = blockIdx.x * 256 + threadIdx.x;
    int p = idx * 16;
    uint4 dq = *reinterpret_cast<const uint4*>(dmap + p);
    if (!(has_byte2(dq.x) | has_byte2(dq.y) | has_byte2(dq.z) | has_byte2(dq.w)))
        return;
    int y = p >> 12;            // p / W
    int xb = p & (W - 1);
    u32 words[4] = {dq.x, dq.y, dq.z, dq.w};
    #pragma unroll
    for (int wi = 0; wi < 4; ++wi) {
        u32 v = words[wi];
        #pragma unroll
        for (int b = 0; b < 4; ++b) {
            if (((v >> (8 * b)) & 0xFFu) == 2u)
                fill_pixel(out, dmap, xb + wi * 4 + b, y, 2);
        }
    }
}

// t=3..16 in ONE single-block kernel over the compacted d>=3 list
// (expected ~0-2 entries).  __syncthreads between rings gives ordering.
__global__ __launch_bounds__(256) void tail_far(
    float* __restrict__ out, const u8* __restrict__ dmap,
    const int* __restrict__ list, const u32* __restrict__ cnt, u32 cap)
{
    u32 n = *cnt;
    if (n > cap) n = cap;
    for (int t = 3; t <= 16; ++t) {
        for (u32 i = threadIdx.x; i < n; i += 256) {
            int p = list[i];
            if (dmap[p] == (u8)t)
                fill_pixel(out, dmap, p & (W - 1), p >> 12, t);
        }
        __syncthreads();
    }
}

extern "C" void kernel_launch(void* const* d_in, const int* in_sizes, int n_in,
                              void* d_out, int out_size, void* d_ws, size_t ws_size,
                              hipStream_t stream) {
    const float* rgb   = (const float*)d_in[0];
    const float* alpha = (const float*)d_in[1];
    float* out = (float*)d_out;

    u8* dmap  = (u8*)d_ws;                           // HW bytes
    u32* cnt  = (u32*)((char*)d_ws + HW);            // 4 bytes (16B slot)
    int* list = (int*)((char*)d_ws + HW + 16);
    u32 cap = 0;
    if (ws_size > (size_t)HW + 16) {
        size_t c = (ws_size - HW - 16) / 4;
        cap = (u32)(c > (1u << 22) ? (1u << 22) : c);
    }

    (void)hipMemsetAsync(cnt, 0, 4, stream);

    pass1_kernel<<<dim3(GRID_X, GRID_Y), dim3(BX, BY), 0, stream>>>(
        rgb, alpha, out, dmap, cnt, list, cap);
    tail_dense<<<HW / 16 / 256, 256, 0, stream>>>(out, dmap);
    tail_far<<<1, 256, 0, stream>>>(out, dmap, list, cnt, cap);
}